// Round 14
// baseline (109.118 us; speedup 1.0000x reference)
//
#include <hip/hip_runtime.h>
#include <math.h>

#define NSLOT 5
#define EPSF 1e-8f
#define TG 4   // samples per tile; one 256-thr block per tile, 4 waves split chunks

typedef float f4 __attribute__((ext_vector_type(4)));

static __device__ __forceinline__ float d4(f4 a, f4 b) {
    return fmaf(a.x, b.x, fmaf(a.y, b.y, fmaf(a.z, b.z, a.w * b.w)));
}

// ---------------- binning kernels ----------------

__global__ void hist_kernel(const int* __restrict__ labels, int* __restrict__ counts, int B) {
    int i = blockIdx.x * blockDim.x + threadIdx.x;
    if (i < B) atomicAdd(&counts[labels[i]], 1);
}

__global__ void scan_kernel(const int* __restrict__ counts, int* __restrict__ offsets,
                            int* __restrict__ cursor, int C) {
    __shared__ int sh[1024];
    __shared__ int running;
    if (threadIdx.x == 0) running = 0;
    __syncthreads();
    for (int base = 0; base < C; base += 1024) {
        int t = base + threadIdx.x;
        int v = (t < C) ? counts[t] : 0;
        sh[threadIdx.x] = v;
        __syncthreads();
        for (int d = 1; d < 1024; d <<= 1) {
            int x = (threadIdx.x >= d) ? sh[threadIdx.x - d] : 0;
            __syncthreads();
            sh[threadIdx.x] += x;
            __syncthreads();
        }
        int excl = sh[threadIdx.x] - v + running;
        if (t < C) { offsets[t] = excl; cursor[t] = excl; }
        __syncthreads();
        if (threadIdx.x == 0) running += sh[1023];
        __syncthreads();
    }
}

__global__ void scan_tasks_kernel(const int* __restrict__ counts, int* __restrict__ toff,
                                  int* __restrict__ nt, int C) {
    __shared__ int sh[1024];
    __shared__ int running;
    if (threadIdx.x == 0) running = 0;
    __syncthreads();
    for (int base = 0; base < C; base += 1024) {
        int t = base + threadIdx.x;
        int v = (t < C) ? ((counts[t] + TG - 1) / TG) : 0;
        sh[threadIdx.x] = v;
        __syncthreads();
        for (int d = 1; d < 1024; d <<= 1) {
            int x = (threadIdx.x >= d) ? sh[threadIdx.x - d] : 0;
            __syncthreads();
            sh[threadIdx.x] += x;
            __syncthreads();
        }
        int excl = sh[threadIdx.x] - v + running;
        if (t < C) toff[t] = excl;
        __syncthreads();
        if (threadIdx.x == 0) running += sh[1023];
        __syncthreads();
    }
    if (threadIdx.x == 0) nt[0] = running;
}

__global__ void scatter_kernel(const int* __restrict__ labels, int* __restrict__ cursor,
                               int* __restrict__ bucket, int B) {
    int i = blockIdx.x * blockDim.x + threadIdx.x;
    if (i < B) {
        int slot = atomicAdd(&cursor[labels[i]], 1);
        bucket[slot] = i;
    }
}

__global__ void fill_tasks_kernel(const int* __restrict__ counts, const int* __restrict__ offsets,
                                  const int* __restrict__ toff,
                                  int* __restrict__ task_c, int* __restrict__ task_j0, int C) {
    int c = blockIdx.x * blockDim.x + threadIdx.x;
    if (c >= C) return;
    int cnt = counts[c];
    int ntc = (cnt + TG - 1) / TG;
    int tb  = toff[c];
    int off = offsets[c];
    for (int t = 0; t < ntc; ++t) {
        task_c[tb + t]  = c;
        task_j0[tb + t] = off + t * TG;
    }
}

// ---------------- main kernel: one block per tile, 4 waves split the chunks ----------------
// Wave w handles chunks {2w, 2w+1}; keys/vals read ONCE per tile; 29 partial
// sums (4 qq + 5 kk + 20 dot) combined via LDS. ~4x the waves of R13 at the
// same byte count -> restores the >=16 waves/CU needed to saturate the per-CU
// miss-service path.

__global__ __launch_bounds__(256, 6) void mb_tile_kernel(
    const float* __restrict__ query,
    const float* __restrict__ mkeys,
    const float* __restrict__ mvals,
    const float* __restrict__ qscores,
    const int*   __restrict__ topk_p,
    const int*   __restrict__ counts,
    const int*   __restrict__ offsets,
    const int*   __restrict__ bucket,
    const int*   __restrict__ task_c,
    const int*   __restrict__ task_j0,
    const int*   __restrict__ nt_p,
    float* __restrict__ out_ret,
    float* __restrict__ out_w)
{
    const int task = blockIdx.x;
    if (task >= nt_p[0]) return;
    const int lane = threadIdx.x & 63;
    const int wave = threadIdx.x >> 6;      // 0..3 -> chunks {2w, 2w+1}

    const int c  = task_c[task];
    const int j0 = task_j0[task];
    const int g  = min(TG, offsets[c] + counts[c] - j0);

    int k = topk_p[0];
    if (k > NSLOT) k = NSLOT;
    if (k < 1) k = 1;

    int idx[TG];
#pragma unroll
    for (int t = 0; t < TG; ++t)
        idx[t] = bucket[j0 + (t < g ? t : g - 1)];

    const f4* kp = reinterpret_cast<const f4*>(mkeys) + (size_t)c * NSLOT * 512;
    const f4* vp = reinterpret_cast<const f4*>(mvals) + (size_t)c * NSLOT * 512;
    const f4* qb = reinterpret_cast<const f4*>(query);

    // ---- pass 1: this wave's 2 chunks; dot[t][s], qq[t], kk[s] ----
    float qq[TG] = {0.f, 0.f, 0.f, 0.f};
    float kk[NSLOT] = {0.f, 0.f, 0.f, 0.f, 0.f};
    float dot[TG][NSLOT];
#pragma unroll
    for (int t = 0; t < TG; ++t)
#pragma unroll
        for (int s = 0; s < NSLOT; ++s) dot[t][s] = 0.f;

#pragma unroll
    for (int mm = 0; mm < 2; ++mm) {
        const int base = (2 * wave + mm) * 64 + lane;
        f4 q[TG];
#pragma unroll
        for (int t = 0; t < TG; ++t) {
            q[t] = qb[(size_t)idx[t] * 512 + base];
            qq[t] = fmaf(q[t].x, q[t].x, fmaf(q[t].y, q[t].y,
                    fmaf(q[t].z, q[t].z, fmaf(q[t].w, q[t].w, qq[t]))));
        }
#pragma unroll
        for (int s = 0; s < NSLOT; ++s) {
            f4 kv = kp[s * 512 + base];
            kk[s] = fmaf(kv.x, kv.x, fmaf(kv.y, kv.y,
                    fmaf(kv.z, kv.z, fmaf(kv.w, kv.w, kk[s]))));
#pragma unroll
            for (int t = 0; t < TG; ++t) {
                dot[t][s] = fmaf(q[t].x, kv.x, fmaf(q[t].y, kv.y,
                            fmaf(q[t].z, kv.z, fmaf(q[t].w, kv.w, dot[t][s]))));
            }
        }
    }

    // ---- butterfly reduce within wave (29 values) ----
#pragma unroll
    for (int o = 1; o < 64; o <<= 1) {
#pragma unroll
        for (int t = 0; t < TG; ++t) {
            qq[t] += __shfl_xor(qq[t], o);
#pragma unroll
            for (int s = 0; s < NSLOT; ++s) dot[t][s] += __shfl_xor(dot[t][s], o);
        }
#pragma unroll
        for (int s = 0; s < NSLOT; ++s) kk[s] += __shfl_xor(kk[s], o);
    }

    // ---- cross-wave combine via LDS ----
    __shared__ float red[4][32];
    if (lane == 0) {
#pragma unroll
        for (int t = 0; t < TG; ++t) red[wave][t] = qq[t];
#pragma unroll
        for (int s = 0; s < NSLOT; ++s) red[wave][4 + s] = kk[s];
#pragma unroll
        for (int t = 0; t < TG; ++t)
#pragma unroll
            for (int s = 0; s < NSLOT; ++s) red[wave][9 + t * NSLOT + s] = dot[t][s];
    }
    __syncthreads();
#pragma unroll
    for (int t = 0; t < TG; ++t)
        qq[t] = red[0][t] + red[1][t] + red[2][t] + red[3][t];
#pragma unroll
    for (int s = 0; s < NSLOT; ++s)
        kk[s] = red[0][4 + s] + red[1][4 + s] + red[2][4 + s] + red[3][4 + s];
#pragma unroll
    for (int t = 0; t < TG; ++t)
#pragma unroll
        for (int s = 0; s < NSLOT; ++s)
            dot[t][s] = red[0][9 + t * NSLOT + s] + red[1][9 + t * NSLOT + s]
                      + red[2][9 + t * NSLOT + s] + red[3][9 + t * NSLOT + s];

    // ---- class-shared epilogue pieces ----
    float scr[NSLOT];
    float ssum = 0.f;
#pragma unroll
    for (int s = 0; s < NSLOT; ++s) {
        scr[s] = qscores[(size_t)c * NSLOT + s];
        ssum += scr[s];
    }
    const bool hit = (ssum != 0.0f);

    float fac[NSLOT];
#pragma unroll
    for (int s = 0; s < NSLOT; ++s)
        fac[s] = scr[s] / fmaxf(sqrtf(kk[s]), EPSF);

    // ---- per-sample epilogue -> wgt[t][s] (redundant on all threads) ----
    float wgt[TG][NSLOT];
#pragma unroll
    for (int t = 0; t < TG; ++t) {
        float qn = fmaxf(sqrtf(qq[t]), EPSF);
        float comb[NSLOT];
#pragma unroll
        for (int s = 0; s < NSLOT; ++s) comb[s] = (dot[t][s] / qn) * fac[s];

        bool used[NSLOT];
#pragma unroll
        for (int s = 0; s < NSLOT; ++s) used[s] = false;
        float tsc[NSLOT];
        int   tix[NSLOT];
#pragma unroll
        for (int jj = 0; jj < NSLOT; ++jj) {
            float best = -INFINITY;
            int bi = 0;
            if (jj < k) {
#pragma unroll
                for (int s = 0; s < NSLOT; ++s) {
                    if (!used[s] && comb[s] > best) { best = comb[s]; bi = s; }
                }
#pragma unroll
                for (int s = 0; s < NSLOT; ++s) used[s] = used[s] || (s == bi);
            }
            tsc[jj] = best;
            tix[jj] = bi;
        }

        float m0 = tsc[0];
        float esum = 0.f, wsum = 0.f;
        float a[NSLOT];
#pragma unroll
        for (int jj = 0; jj < NSLOT; ++jj) {
            if (jj < k) {
                a[jj] = __expf((tsc[jj] - m0) * 10.0f);   // 1/TEMP = 10
                esum += a[jj];
                wsum += tsc[jj];
            } else {
                a[jj] = 0.f;
            }
        }
        float inv = hit ? (1.0f / esum) : 0.0f;
#pragma unroll
        for (int s = 0; s < NSLOT; ++s) {
            float wsv = 0.f;
#pragma unroll
            for (int jj = 0; jj < NSLOT; ++jj)
                if (jj < k && tix[jj] == s) wsv += a[jj] * inv;
            wgt[t][s] = wsv;
        }

        if (threadIdx.x == 0 && t < g) out_w[idx[t]] = hit ? (wsum / (float)k) : 0.0f;
    }

    // ---- pass 2: this wave's 2 chunks; values read once, applied to all ----
#pragma unroll
    for (int mm = 0; mm < 2; ++mm) {
        const int base = (2 * wave + mm) * 64 + lane;
        f4 v[NSLOT];
#pragma unroll
        for (int s = 0; s < NSLOT; ++s) v[s] = vp[s * 512 + base];
#pragma unroll
        for (int t = 0; t < TG; ++t) {
            if (t < g) {
                f4 acc = (f4)(0.f);
#pragma unroll
                for (int s = 0; s < NSLOT; ++s) {
                    acc.x = fmaf(wgt[t][s], v[s].x, acc.x);
                    acc.y = fmaf(wgt[t][s], v[s].y, acc.y);
                    acc.z = fmaf(wgt[t][s], v[s].z, acc.z);
                    acc.w = fmaf(wgt[t][s], v[s].w, acc.w);
                }
                reinterpret_cast<f4*>(out_ret)[(size_t)idx[t] * 512 + base] = acc;
            }
        }
    }
}

// ---------------- generic fallback (any D), sample-centric ----------------

__global__ __launch_bounds__(64) void mb_generic_kernel(
    const float* __restrict__ query,
    const int*   __restrict__ labels,
    const float* __restrict__ mkeys,
    const float* __restrict__ mvals,
    const float* __restrict__ qscores,
    const int*   __restrict__ topk_p,
    float* __restrict__ out_ret,
    float* __restrict__ out_w,
    int B, int n4)
{
    const int lane = threadIdx.x;
    const int i    = blockIdx.x;
    if (i >= B) return;
    const int c = labels[i];
    int k = topk_p[0];
    if (k > NSLOT) k = NSLOT;
    if (k < 1) k = 1;

    const f4* q4 = reinterpret_cast<const f4*>(query) + (size_t)i * n4;
    const f4* k4 = reinterpret_cast<const f4*>(mkeys) + (size_t)c * NSLOT * n4;
    const f4* v4 = reinterpret_cast<const f4*>(mvals) + (size_t)c * NSLOT * n4;
    f4*       o4 = reinterpret_cast<f4*>(out_ret) + (size_t)i * n4;

    float qq = 0.f, dot[NSLOT] = {0}, kk[NSLOT] = {0};
    for (int idx = lane; idx < n4; idx += 64) {
        f4 q = q4[idx];
        qq += d4(q, q);
        for (int s = 0; s < NSLOT; ++s) {
            f4 t = k4[s * n4 + idx];
            dot[s] += d4(q, t);
            kk[s]  += d4(t, t);
        }
    }
    for (int o = 1; o < 64; o <<= 1) {
        qq += __shfl_xor(qq, o);
        for (int s = 0; s < NSLOT; ++s) {
            dot[s] += __shfl_xor(dot[s], o);
            kk[s]  += __shfl_xor(kk[s], o);
        }
    }
    float qn = fmaxf(sqrtf(qq), EPSF);
    float scr[NSLOT], ssum = 0.f;
    for (int s = 0; s < NSLOT; ++s) { scr[s] = qscores[(size_t)c * NSLOT + s]; ssum += scr[s]; }
    float comb[NSLOT];
    for (int s = 0; s < NSLOT; ++s)
        comb[s] = (dot[s] / (qn * fmaxf(sqrtf(kk[s]), EPSF))) * scr[s];
    bool used[NSLOT] = {false, false, false, false, false};
    float tsc[NSLOT]; int tix[NSLOT];
    for (int jj = 0; jj < NSLOT; ++jj) {
        float best = -INFINITY; int bi = 0;
        if (jj < k) {
            for (int s = 0; s < NSLOT; ++s)
                if (!used[s] && comb[s] > best) { best = comb[s]; bi = s; }
            used[bi] = true;
        }
        tsc[jj] = best; tix[jj] = bi;
    }
    const bool hit = (ssum != 0.0f);
    float m = tsc[0], esum = 0.f, wsum = 0.f, a[NSLOT];
    for (int jj = 0; jj < NSLOT; ++jj) {
        if (jj < k) { a[jj] = __expf((tsc[jj] - m) * 10.0f); esum += a[jj]; wsum += tsc[jj]; }
        else a[jj] = 0.f;
    }
    float inv = hit ? (1.0f / esum) : 0.0f;
    float w[NSLOT];
    for (int s = 0; s < NSLOT; ++s) {
        float wsv = 0.f;
        for (int jj = 0; jj < NSLOT; ++jj) if (jj < k && tix[jj] == s) wsv += a[jj] * inv;
        w[s] = wsv;
    }
    if (lane == 0) out_w[i] = hit ? (wsum / (float)k) : 0.0f;
    for (int idx = lane; idx < n4; idx += 64) {
        f4 acc = (f4)(0.f);
        for (int s = 0; s < NSLOT; ++s) {
            f4 v = v4[s * n4 + idx];
            acc += v * w[s];
        }
        o4[idx] = acc;
    }
}

extern "C" void kernel_launch(void* const* d_in, const int* in_sizes, int n_in,
                              void* d_out, int out_size, void* d_ws, size_t ws_size,
                              hipStream_t stream) {
    const float* query   = (const float*)d_in[0];
    const int*   labels  = (const int*)d_in[1];
    const float* mkeys   = (const float*)d_in[2];
    const float* mvals   = (const float*)d_in[3];
    const float* qscores = (const float*)d_in[4];
    const int*   topk    = (const int*)d_in[5];

    const int B  = in_sizes[1];
    const int D  = in_sizes[0] / B;
    const int n4 = D >> 2;
    const int C  = in_sizes[4] / NSLOT;

    float* out_ret = (float*)d_out;
    float* out_w   = out_ret + (size_t)B * D;

    const int TMAX = (B + (TG - 1) * C) / TG + 8;
    const size_t need = (size_t)(4 * C + B + 1 + 2 * TMAX) * sizeof(int);

    if (D == 2048 && need <= ws_size) {
        int* counts  = (int*)d_ws;          // C
        int* offsets = counts + C;          // C
        int* cursor  = offsets + C;         // C
        int* toff    = cursor + C;          // C
        int* nt      = toff + C;            // 1
        int* bucket  = nt + 1;              // B
        int* task_c  = bucket + B;          // TMAX
        int* task_j0 = task_c + TMAX;       // TMAX

        hipMemsetAsync(counts, 0, (size_t)C * sizeof(int), stream);
        hist_kernel<<<dim3((B + 255) / 256), dim3(256), 0, stream>>>(labels, counts, B);
        scan_kernel<<<dim3(1), dim3(1024), 0, stream>>>(counts, offsets, cursor, C);
        scan_tasks_kernel<<<dim3(1), dim3(1024), 0, stream>>>(counts, toff, nt, C);
        scatter_kernel<<<dim3((B + 255) / 256), dim3(256), 0, stream>>>(labels, cursor, bucket, B);
        fill_tasks_kernel<<<dim3((C + 255) / 256), dim3(256), 0, stream>>>(
            counts, offsets, toff, task_c, task_j0, C);

        mb_tile_kernel<<<dim3(TMAX), dim3(256), 0, stream>>>(
            query, mkeys, mvals, qscores, topk, counts, offsets, bucket,
            task_c, task_j0, nt, out_ret, out_w);
    } else {
        mb_generic_kernel<<<dim3(B), dim3(64), 0, stream>>>(
            query, labels, mkeys, mvals, qscores, topk, out_ret, out_w, B, n4);
    }
}

// Round 15
// 53.198 us; speedup vs baseline: 2.0512x; 2.0512x over previous
//
#include <hip/hip_runtime.h>
#include <math.h>

#define NSLOT 5
#define EPSF 1e-8f
#define TG 4   // samples per tile; one 256-thr block per tile, 4 waves split chunks

typedef float f4 __attribute__((ext_vector_type(4)));

static __device__ __forceinline__ float d4(f4 a, f4 b) {
    return fmaf(a.x, b.x, fmaf(a.y, b.y, fmaf(a.z, b.z, a.w * b.w)));
}

// ---------------- binning kernels ----------------

__global__ void hist_kernel(const int* __restrict__ labels, int* __restrict__ counts, int B) {
    int i = blockIdx.x * blockDim.x + threadIdx.x;
    if (i < B) atomicAdd(&counts[labels[i]], 1);
}

__global__ void scan_kernel(const int* __restrict__ counts, int* __restrict__ offsets,
                            int* __restrict__ cursor, int C) {
    __shared__ int sh[1024];
    __shared__ int running;
    if (threadIdx.x == 0) running = 0;
    __syncthreads();
    for (int base = 0; base < C; base += 1024) {
        int t = base + threadIdx.x;
        int v = (t < C) ? counts[t] : 0;
        sh[threadIdx.x] = v;
        __syncthreads();
        for (int d = 1; d < 1024; d <<= 1) {
            int x = (threadIdx.x >= d) ? sh[threadIdx.x - d] : 0;
            __syncthreads();
            sh[threadIdx.x] += x;
            __syncthreads();
        }
        int excl = sh[threadIdx.x] - v + running;
        if (t < C) { offsets[t] = excl; cursor[t] = excl; }
        __syncthreads();
        if (threadIdx.x == 0) running += sh[1023];
        __syncthreads();
    }
}

__global__ void scan_tasks_kernel(const int* __restrict__ counts, int* __restrict__ toff,
                                  int* __restrict__ nt, int C) {
    __shared__ int sh[1024];
    __shared__ int running;
    if (threadIdx.x == 0) running = 0;
    __syncthreads();
    for (int base = 0; base < C; base += 1024) {
        int t = base + threadIdx.x;
        int v = (t < C) ? ((counts[t] + TG - 1) / TG) : 0;
        sh[threadIdx.x] = v;
        __syncthreads();
        for (int d = 1; d < 1024; d <<= 1) {
            int x = (threadIdx.x >= d) ? sh[threadIdx.x - d] : 0;
            __syncthreads();
            sh[threadIdx.x] += x;
            __syncthreads();
        }
        int excl = sh[threadIdx.x] - v + running;
        if (t < C) toff[t] = excl;
        __syncthreads();
        if (threadIdx.x == 0) running += sh[1023];
        __syncthreads();
    }
    if (threadIdx.x == 0) nt[0] = running;
}

__global__ void scatter_kernel(const int* __restrict__ labels, int* __restrict__ cursor,
                               int* __restrict__ bucket, int B) {
    int i = blockIdx.x * blockDim.x + threadIdx.x;
    if (i < B) {
        int slot = atomicAdd(&cursor[labels[i]], 1);
        bucket[slot] = i;
    }
}

__global__ void fill_tasks_kernel(const int* __restrict__ counts, const int* __restrict__ offsets,
                                  const int* __restrict__ toff,
                                  int* __restrict__ task_c, int* __restrict__ task_j0, int C) {
    int c = blockIdx.x * blockDim.x + threadIdx.x;
    if (c >= C) return;
    int cnt = counts[c];
    int ntc = (cnt + TG - 1) / TG;
    int tb  = toff[c];
    int off = offsets[c];
    for (int t = 0; t < ntc; ++t) {
        task_c[tb + t]  = c;
        task_j0[tb + t] = off + t * TG;
    }
}

// ---------------- main kernel ----------------
// One block per tile (<=4 same-class samples), 4 waves split the 8 chunks of D.
// Keys/vals read ONCE per tile. Cross-wave partials via LDS. Epilogue is
// DISTRIBUTED: wave w computes only sample w's top-k/softmax (inputs from LDS),
// writes wgt[w][*] to LDS; pass 2 reads wgt from LDS. Keeps peak VGPR ~70,
// launch_bounds(256,4) caps at 128 -> no spill (R14's failure).

__global__ __launch_bounds__(256, 4) void mb_tile_kernel(
    const float* __restrict__ query,
    const float* __restrict__ mkeys,
    const float* __restrict__ mvals,
    const float* __restrict__ qscores,
    const int*   __restrict__ topk_p,
    const int*   __restrict__ counts,
    const int*   __restrict__ offsets,
    const int*   __restrict__ bucket,
    const int*   __restrict__ task_c,
    const int*   __restrict__ task_j0,
    const int*   __restrict__ nt_p,
    float* __restrict__ out_ret,
    float* __restrict__ out_w)
{
    const int task = blockIdx.x;
    if (task >= nt_p[0]) return;
    const int lane = threadIdx.x & 63;
    const int wave = threadIdx.x >> 6;      // 0..3 -> chunks {2w, 2w+1}

    const int c  = task_c[task];
    const int j0 = task_j0[task];
    const int g  = min(TG, offsets[c] + counts[c] - j0);

    int k = topk_p[0];
    if (k > NSLOT) k = NSLOT;
    if (k < 1) k = 1;

    int idx[TG];
#pragma unroll
    for (int t = 0; t < TG; ++t)
        idx[t] = bucket[j0 + (t < g ? t : g - 1)];   // replicate last when short

    const f4* kp = reinterpret_cast<const f4*>(mkeys) + (size_t)c * NSLOT * 512;
    const f4* vp = reinterpret_cast<const f4*>(mvals) + (size_t)c * NSLOT * 512;
    const f4* qb = reinterpret_cast<const f4*>(query);

    // ---- pass 1: this wave's 2 chunks; dot[t][s], qq[t], kk[s] ----
    float qq[TG] = {0.f, 0.f, 0.f, 0.f};
    float kk[NSLOT] = {0.f, 0.f, 0.f, 0.f, 0.f};
    float dot[TG][NSLOT];
#pragma unroll
    for (int t = 0; t < TG; ++t)
#pragma unroll
        for (int s = 0; s < NSLOT; ++s) dot[t][s] = 0.f;

#pragma unroll
    for (int mm = 0; mm < 2; ++mm) {
        const int base = (2 * wave + mm) * 64 + lane;
        f4 q[TG];
#pragma unroll
        for (int t = 0; t < TG; ++t) {
            q[t] = qb[(size_t)idx[t] * 512 + base];
            qq[t] = fmaf(q[t].x, q[t].x, fmaf(q[t].y, q[t].y,
                    fmaf(q[t].z, q[t].z, fmaf(q[t].w, q[t].w, qq[t]))));
        }
#pragma unroll
        for (int s = 0; s < NSLOT; ++s) {
            f4 kv = kp[s * 512 + base];
            kk[s] = fmaf(kv.x, kv.x, fmaf(kv.y, kv.y,
                    fmaf(kv.z, kv.z, fmaf(kv.w, kv.w, kk[s]))));
#pragma unroll
            for (int t = 0; t < TG; ++t) {
                dot[t][s] = fmaf(q[t].x, kv.x, fmaf(q[t].y, kv.y,
                            fmaf(q[t].z, kv.z, fmaf(q[t].w, kv.w, dot[t][s]))));
            }
        }
    }

    // ---- butterfly reduce within wave (29 values) ----
#pragma unroll
    for (int o = 1; o < 64; o <<= 1) {
#pragma unroll
        for (int t = 0; t < TG; ++t) {
            qq[t] += __shfl_xor(qq[t], o);
#pragma unroll
            for (int s = 0; s < NSLOT; ++s) dot[t][s] += __shfl_xor(dot[t][s], o);
        }
#pragma unroll
        for (int s = 0; s < NSLOT; ++s) kk[s] += __shfl_xor(kk[s], o);
    }

    // ---- cross-wave combine via LDS ----
    __shared__ float red[4][32];
    __shared__ float wgt_lds[TG][NSLOT];
    if (lane == 0) {
#pragma unroll
        for (int t = 0; t < TG; ++t) red[wave][t] = qq[t];
#pragma unroll
        for (int s = 0; s < NSLOT; ++s) red[wave][4 + s] = kk[s];
#pragma unroll
        for (int t = 0; t < TG; ++t)
#pragma unroll
            for (int s = 0; s < NSLOT; ++s) red[wave][9 + t * NSLOT + s] = dot[t][s];
    }
    __syncthreads();

    // ---- distributed epilogue: wave w handles sample w ----
    {
        const int t = wave;    // sample index this wave owns
        float qqt = red[0][t] + red[1][t] + red[2][t] + red[3][t];
        float kkt[NSLOT], dott[NSLOT];
#pragma unroll
        for (int s = 0; s < NSLOT; ++s) {
            kkt[s]  = red[0][4 + s] + red[1][4 + s] + red[2][4 + s] + red[3][4 + s];
            dott[s] = red[0][9 + t * NSLOT + s] + red[1][9 + t * NSLOT + s]
                    + red[2][9 + t * NSLOT + s] + red[3][9 + t * NSLOT + s];
        }

        float scr[NSLOT];
        float ssum = 0.f;
#pragma unroll
        for (int s = 0; s < NSLOT; ++s) {
            scr[s] = qscores[(size_t)c * NSLOT + s];
            ssum += scr[s];
        }
        const bool hit = (ssum != 0.0f);

        float qn = fmaxf(sqrtf(qqt), EPSF);
        float comb[NSLOT];
#pragma unroll
        for (int s = 0; s < NSLOT; ++s)
            comb[s] = (dott[s] / qn) * (scr[s] / fmaxf(sqrtf(kkt[s]), EPSF));

        bool used[NSLOT];
#pragma unroll
        for (int s = 0; s < NSLOT; ++s) used[s] = false;
        float tsc[NSLOT];
        int   tix[NSLOT];
#pragma unroll
        for (int jj = 0; jj < NSLOT; ++jj) {
            float best = -INFINITY;
            int bi = 0;
            if (jj < k) {
#pragma unroll
                for (int s = 0; s < NSLOT; ++s) {
                    if (!used[s] && comb[s] > best) { best = comb[s]; bi = s; }
                }
#pragma unroll
                for (int s = 0; s < NSLOT; ++s) used[s] = used[s] || (s == bi);
            }
            tsc[jj] = best;
            tix[jj] = bi;
        }

        float m0 = tsc[0];
        float esum = 0.f, wsum = 0.f;
        float a[NSLOT];
#pragma unroll
        for (int jj = 0; jj < NSLOT; ++jj) {
            if (jj < k) {
                a[jj] = __expf((tsc[jj] - m0) * 10.0f);   // 1/TEMP = 10
                esum += a[jj];
                wsum += tsc[jj];
            } else {
                a[jj] = 0.f;
            }
        }
        float inv = hit ? (1.0f / esum) : 0.0f;

        if (lane == 0) {
#pragma unroll
            for (int s = 0; s < NSLOT; ++s) {
                float wsv = 0.f;
#pragma unroll
                for (int jj = 0; jj < NSLOT; ++jj)
                    if (jj < k && tix[jj] == s) wsv += a[jj] * inv;
                wgt_lds[t][s] = wsv;
            }
            if (t < g) out_w[idx[t]] = hit ? (wsum / (float)k) : 0.0f;
        }
    }
    __syncthreads();

    // ---- pass 2: this wave's 2 chunks; values read once, applied to all ----
#pragma unroll
    for (int mm = 0; mm < 2; ++mm) {
        const int base = (2 * wave + mm) * 64 + lane;
        f4 v0 = vp[0 * 512 + base];
        f4 v1 = vp[1 * 512 + base];
        f4 v2 = vp[2 * 512 + base];
        f4 v3 = vp[3 * 512 + base];
        f4 v4 = vp[4 * 512 + base];
#pragma unroll
        for (int t = 0; t < TG; ++t) {
            if (t < g) {
                const float w0 = wgt_lds[t][0], w1 = wgt_lds[t][1], w2 = wgt_lds[t][2];
                const float w3 = wgt_lds[t][3], w4 = wgt_lds[t][4];
                f4 acc;
                acc.x = fmaf(w0, v0.x, fmaf(w1, v1.x, fmaf(w2, v2.x, fmaf(w3, v3.x, w4 * v4.x))));
                acc.y = fmaf(w0, v0.y, fmaf(w1, v1.y, fmaf(w2, v2.y, fmaf(w3, v3.y, w4 * v4.y))));
                acc.z = fmaf(w0, v0.z, fmaf(w1, v1.z, fmaf(w2, v2.z, fmaf(w3, v3.z, w4 * v4.z))));
                acc.w = fmaf(w0, v0.w, fmaf(w1, v1.w, fmaf(w2, v2.w, fmaf(w3, v3.w, w4 * v4.w))));
                reinterpret_cast<f4*>(out_ret)[(size_t)idx[t] * 512 + base] = acc;
            }
        }
    }
}

// ---------------- generic fallback (any D), sample-centric ----------------

__global__ __launch_bounds__(64) void mb_generic_kernel(
    const float* __restrict__ query,
    const int*   __restrict__ labels,
    const float* __restrict__ mkeys,
    const float* __restrict__ mvals,
    const float* __restrict__ qscores,
    const int*   __restrict__ topk_p,
    float* __restrict__ out_ret,
    float* __restrict__ out_w,
    int B, int n4)
{
    const int lane = threadIdx.x;
    const int i    = blockIdx.x;
    if (i >= B) return;
    const int c = labels[i];
    int k = topk_p[0];
    if (k > NSLOT) k = NSLOT;
    if (k < 1) k = 1;

    const f4* q4 = reinterpret_cast<const f4*>(query) + (size_t)i * n4;
    const f4* k4 = reinterpret_cast<const f4*>(mkeys) + (size_t)c * NSLOT * n4;
    const f4* v4 = reinterpret_cast<const f4*>(mvals) + (size_t)c * NSLOT * n4;
    f4*       o4 = reinterpret_cast<f4*>(out_ret) + (size_t)i * n4;

    float qq = 0.f, dot[NSLOT] = {0}, kk[NSLOT] = {0};
    for (int idx = lane; idx < n4; idx += 64) {
        f4 q = q4[idx];
        qq += d4(q, q);
        for (int s = 0; s < NSLOT; ++s) {
            f4 t = k4[s * n4 + idx];
            dot[s] += d4(q, t);
            kk[s]  += d4(t, t);
        }
    }
    for (int o = 1; o < 64; o <<= 1) {
        qq += __shfl_xor(qq, o);
        for (int s = 0; s < NSLOT; ++s) {
            dot[s] += __shfl_xor(dot[s], o);
            kk[s]  += __shfl_xor(kk[s], o);
        }
    }
    float qn = fmaxf(sqrtf(qq), EPSF);
    float scr[NSLOT], ssum = 0.f;
    for (int s = 0; s < NSLOT; ++s) { scr[s] = qscores[(size_t)c * NSLOT + s]; ssum += scr[s]; }
    float comb[NSLOT];
    for (int s = 0; s < NSLOT; ++s)
        comb[s] = (dot[s] / (qn * fmaxf(sqrtf(kk[s]), EPSF))) * scr[s];
    bool used[NSLOT] = {false, false, false, false, false};
    float tsc[NSLOT]; int tix[NSLOT];
    for (int jj = 0; jj < NSLOT; ++jj) {
        float best = -INFINITY; int bi = 0;
        if (jj < k) {
            for (int s = 0; s < NSLOT; ++s)
                if (!used[s] && comb[s] > best) { best = comb[s]; bi = s; }
            used[bi] = true;
        }
        tsc[jj] = best; tix[jj] = bi;
    }
    const bool hit = (ssum != 0.0f);
    float m = tsc[0], esum = 0.f, wsum = 0.f, a[NSLOT];
    for (int jj = 0; jj < NSLOT; ++jj) {
        if (jj < k) { a[jj] = __expf((tsc[jj] - m) * 10.0f); esum += a[jj]; wsum += tsc[jj]; }
        else a[jj] = 0.f;
    }
    float inv = hit ? (1.0f / esum) : 0.0f;
    float w[NSLOT];
    for (int s = 0; s < NSLOT; ++s) {
        float wsv = 0.f;
        for (int jj = 0; jj < NSLOT; ++jj) if (jj < k && tix[jj] == s) wsv += a[jj] * inv;
        w[s] = wsv;
    }
    if (lane == 0) out_w[i] = hit ? (wsum / (float)k) : 0.0f;
    for (int idx = lane; idx < n4; idx += 64) {
        f4 acc = (f4)(0.f);
        for (int s = 0; s < NSLOT; ++s) {
            f4 v = v4[s * n4 + idx];
            acc += v * w[s];
        }
        o4[idx] = acc;
    }
}

extern "C" void kernel_launch(void* const* d_in, const int* in_sizes, int n_in,
                              void* d_out, int out_size, void* d_ws, size_t ws_size,
                              hipStream_t stream) {
    const float* query   = (const float*)d_in[0];
    const int*   labels  = (const int*)d_in[1];
    const float* mkeys   = (const float*)d_in[2];
    const float* mvals   = (const float*)d_in[3];
    const float* qscores = (const float*)d_in[4];
    const int*   topk    = (const int*)d_in[5];

    const int B  = in_sizes[1];
    const int D  = in_sizes[0] / B;
    const int n4 = D >> 2;
    const int C  = in_sizes[4] / NSLOT;

    float* out_ret = (float*)d_out;
    float* out_w   = out_ret + (size_t)B * D;

    const int TMAX = (B + (TG - 1) * C) / TG + 8;
    const size_t need = (size_t)(4 * C + B + 1 + 2 * TMAX) * sizeof(int);

    if (D == 2048 && need <= ws_size) {
        int* counts  = (int*)d_ws;          // C
        int* offsets = counts + C;          // C
        int* cursor  = offsets + C;         // C
        int* toff    = cursor + C;          // C
        int* nt      = toff + C;            // 1
        int* bucket  = nt + 1;              // B
        int* task_c  = bucket + B;          // TMAX
        int* task_j0 = task_c + TMAX;       // TMAX

        hipMemsetAsync(counts, 0, (size_t)C * sizeof(int), stream);
        hist_kernel<<<dim3((B + 255) / 256), dim3(256), 0, stream>>>(labels, counts, B);
        scan_kernel<<<dim3(1), dim3(1024), 0, stream>>>(counts, offsets, cursor, C);
        scan_tasks_kernel<<<dim3(1), dim3(1024), 0, stream>>>(counts, toff, nt, C);
        scatter_kernel<<<dim3((B + 255) / 256), dim3(256), 0, stream>>>(labels, cursor, bucket, B);
        fill_tasks_kernel<<<dim3((C + 255) / 256), dim3(256), 0, stream>>>(
            counts, offsets, toff, task_c, task_j0, C);

        mb_tile_kernel<<<dim3(TMAX), dim3(256), 0, stream>>>(
            query, mkeys, mvals, qscores, topk, counts, offsets, bucket,
            task_c, task_j0, nt, out_ret, out_w);
    } else {
        mb_generic_kernel<<<dim3(B), dim3(64), 0, stream>>>(
            query, labels, mkeys, mvals, qscores, topk, out_ret, out_w, B, n4);
    }
}